// Round 2
// baseline (177.647 us; speedup 1.0000x reference)
//
#include <hip/hip_runtime.h>
#include <stdint.h>
#include <stddef.h>

// Problem constants (match reference).
#define Bn 32
#define Tn 512
#define Vn 64
#define Fn 64
#define TT 8    // timesteps per workgroup -> grid = 32 * 64 = 2048 blocks

typedef __attribute__((ext_vector_type(8))) short bfx8;  // 8 bf16 (4 VGPRs)
typedef __attribute__((ext_vector_type(4))) float fx4;   // MFMA accumulator
typedef __attribute__((ext_vector_type(4))) int   ix4;

// fp32 -> bf16, round-to-nearest-even
__device__ __forceinline__ short f2bf(float f) {
    union { float f; uint32_t u; } c; c.f = f;
    uint32_t u = c.u;
    return (short)((u + 0x7FFFu + ((u >> 16) & 1u)) >> 16);
}
// pack two fp32 -> one dword of 2 bf16 (lo = a, hi = b)
__device__ __forceinline__ int pkbf(float a, float b) {
    uint32_t lo = (uint32_t)(uint16_t)f2bf(a);
    uint32_t hi = (uint32_t)(uint16_t)f2bf(b);
    return (int)(lo | (hi << 16));
}

// LDS budget: exactly 40960 B -> 4 blocks/CU (160 KiB).
// Setup-phase data (wt/ps/dg) dies before Theta frags (tf) are written.
union Shmem {
    struct { float wt[64][65]; float ps[4][64]; float dg[64]; } s;  // 17920 B
    short tf[32][64][8];                                            // 32768 B
};

__global__ __launch_bounds__(256, 4) void gcjk_main(
    const float* __restrict__ x, const float* __restrict__ W,
    const float* __restrict__ Theta, float* __restrict__ out)
{
    __shared__ __align__(16) Shmem sm;
    __shared__ __align__(16) short xt[64 * 64];   // Xt[f][u] bf16, XOR-swizzled, 8192 B

    const int tid  = threadIdx.x;
    const int lane = tid & 63;
    const int wv   = tid >> 6;     // wave id: v-block, staging u-slab, colsum segment
    const int l15  = lane & 15;
    const int gg   = lane >> 4;

    const int bid = blockIdx.x;
    const int b   = bid >> 6;          // 64 chunks per b
    const int t0  = (bid & 63) * TT;

    // ---- setup: load W[b] into LDS (coalesced float4) ----
    const float4* W4 = (const float4*)(W + b * (Vn * Vn));
    #pragma unroll
    for (int c = 0; c < 4; ++c) {
        float4 wq = W4[c * 256 + tid];
        int flat = (c * 256 + tid) * 4;
        int i = flat >> 6, j = flat & 63;
        sm.s.wt[i][j+0] = wq.x; sm.s.wt[i][j+1] = wq.y;
        sm.s.wt[i][j+2] = wq.z; sm.s.wt[i][j+3] = wq.w;
    }
    __syncthreads();

    // column sums (deg[j] = sum_i W[i][j]), parallel 2-phase
    {
        float s = 0.f;
        #pragma unroll
        for (int r = 0; r < 16; ++r) s += sm.s.wt[wv * 16 + r][lane];
        sm.s.ps[wv][lane] = s;
    }
    __syncthreads();
    if (tid < 64) sm.s.dg[tid] = sm.s.ps[0][tid] + sm.s.ps[1][tid] + sm.s.ps[2][tid] + sm.s.ps[3][tid];
    __syncthreads();

    // ---- A fragments (stage-1 B-operand) in registers, reused for all t ----
    // af[k][s] element e = T_k[u = 32s+8gg+e][v = 16wv+l15]
    bfx8 af[4][2];
    {
        const int v = 16 * wv + l15;
        #pragma unroll
        for (int s = 0; s < 2; ++s) {
            #pragma unroll
            for (int e = 0; e < 8; ++e) {
                int u = 32 * s + 8 * gg + e;
                float wuv = sm.s.wt[u][v];
                float lt  = ((u == v) ? (sm.s.dg[u] - 1.0f) : 0.0f) - wuv;  // D - W - I
                float p0  = (u == v) ? 1.0f : 0.0f;
                float p1  = lt;
                float p2  = 2.0f * lt * p1 - p0;   // elementwise Chebyshev
                float p3  = 2.0f * lt * p2 - p1;
                af[0][s][e] = f2bf(p0);
                af[1][s][e] = f2bf(p1);
                af[2][s][e] = f2bf(p2);
                af[3][s][e] = f2bf(p3);
            }
        }
    }
    __syncthreads();   // wt/ps/dg dead; union becomes tf

    // ---- Theta fragments (stage-2 A-operand) into LDS, per-lane read order ----
    #pragma unroll
    for (int fi = 0; fi < 8; ++fi) {
        int frag = wv * 8 + fi;
        int gt = frag >> 3, k = (frag >> 1) & 3, fh = frag & 1;
        int g  = 16 * gt + l15;
        #pragma unroll
        for (int e = 0; e < 8; ++e) {
            int f = 16 * (2 * fh + (e >> 2)) + 4 * gg + (e & 3);
            sm.tf[frag][lane][e] = f2bf(Theta[(k * Fn + f) * Fn + g]);
        }
    }

    // ---- initial staging of tile t0 into xt ----
    // thread (sf = lane, sw = wv): 16 u-contiguous floats at fixed f = sf
    const int sf = lane, sw = wv;
    const float* xs = x + (size_t)(b * Tn + t0) * (Vn * Fn);
    {
        float v0[16];
        #pragma unroll
        for (int j = 0; j < 16; ++j) v0[j] = xs[(16 * sw + j) * Fn + sf];
        #pragma unroll
        for (int r = 0; r < 4; ++r) {
            int2 dv; dv.x = pkbf(v0[4*r+0], v0[4*r+1]); dv.y = pkbf(v0[4*r+2], v0[4*r+3]);
            int g = (4 * sw + r) ^ (sf & 15);          // 8B-granule XOR swizzle
            *(int2*)&xt[sf * 64 + g * 4] = dv;
        }
    }
    __syncthreads();

    // ---- main t loop: single-buffered xt, issue-early / write-late prefetch ----
    for (int ts = 0; ts < TT; ++ts) {
        const float* xb = xs + (size_t)ts * (Vn * Fn);

        // issue next tile's global loads early (hide under MFMA)
        float pre[16];
        if (ts + 1 < TT) {
            const float* xn = xb + (Vn * Fn);
            #pragma unroll
            for (int j = 0; j < 16; ++j) pre[j] = xn[(16 * sw + j) * Fn + sf];
        }

        // X fragments: rows f = 16ft+l15, cols u = 32s+8gg..+7 (swizzled 2x b64)
        bfx8 xf[4][2];
        #pragma unroll
        for (int ft = 0; ft < 4; ++ft) {
            const int f = 16 * ft + l15;
            #pragma unroll
            for (int s = 0; s < 2; ++s) {
                int ub = 8 * s + 2 * gg;               // u0>>2
                int g0 = (ub    ) ^ (f & 15);
                int g1 = (ub + 1) ^ (f & 15);
                int2 lo = *(const int2*)&xt[f * 64 + g0 * 4];
                int2 hi = *(const int2*)&xt[f * 64 + g1 * 4];
                ix4 q; q[0] = lo.x; q[1] = lo.y; q[2] = hi.x; q[3] = hi.y;
                xf[ft][s] = *(bfx8*)&q;
            }
        }

        fx4 oacc[4] = {fx4{0,0,0,0}, fx4{0,0,0,0}, fx4{0,0,0,0}, fx4{0,0,0,0}};
        #pragma unroll
        for (int k = 0; k < 4; ++k) {
            // stage 1: PT_k[f][v] = sum_u Xt[f][u] * T_k[u][v]
            fx4 pacc[4] = {fx4{0,0,0,0}, fx4{0,0,0,0}, fx4{0,0,0,0}, fx4{0,0,0,0}};
            #pragma unroll
            for (int ft = 0; ft < 4; ++ft) {
                pacc[ft] = __builtin_amdgcn_mfma_f32_16x16x32_bf16(xf[ft][0], af[k][0], pacc[ft], 0, 0, 0);
                pacc[ft] = __builtin_amdgcn_mfma_f32_16x16x32_bf16(xf[ft][1], af[k][1], pacc[ft], 0, 0, 0);
            }
            // stage 2: out'[g][v] += Theta'[g][kf] * PT[kf][v]  (pure register repack)
            #pragma unroll
            for (int fh = 0; fh < 2; ++fh) {
                fx4 pa = pacc[2*fh], pb = pacc[2*fh+1];
                ix4 pq;
                pq[0] = pkbf(pa[0], pa[1]); pq[1] = pkbf(pa[2], pa[3]);
                pq[2] = pkbf(pb[0], pb[1]); pq[3] = pkbf(pb[2], pb[3]);
                bfx8 pf = *(bfx8*)&pq;
                #pragma unroll
                for (int gt = 0; gt < 4; ++gt) {
                    bfx8 th = *(const bfx8*)&sm.tf[gt*8 + k*2 + fh][lane][0];
                    oacc[gt] = __builtin_amdgcn_mfma_f32_16x16x32_bf16(th, pf, oacc[gt], 0, 0, 0);
                }
            }
        }

        // epilogue: relu(out) + sigmoid(x), packed float4 (x re-read is L1/L2-hot)
        {
            const int v = 16 * wv + l15;
            float* ob = out + (size_t)(b * Tn + t0 + ts) * (Vn * Fn);
            #pragma unroll
            for (int gt = 0; gt < 4; ++gt) {
                int g0 = 16 * gt + 4 * gg;
                float4 xv = *(const float4*)(xb + v * Fn + g0);
                fx4 o = oacc[gt];
                float4 r;
                r.x = fmaxf(o[0], 0.f) + __builtin_amdgcn_rcpf(1.f + __expf(-xv.x));
                r.y = fmaxf(o[1], 0.f) + __builtin_amdgcn_rcpf(1.f + __expf(-xv.y));
                r.z = fmaxf(o[2], 0.f) + __builtin_amdgcn_rcpf(1.f + __expf(-xv.z));
                r.w = fmaxf(o[3], 0.f) + __builtin_amdgcn_rcpf(1.f + __expf(-xv.w));
                *(float4*)(ob + v * Fn + g0) = r;
            }
        }

        // convert prefetched tile (register-only), then commit after barrier
        int2 dnx[4];
        if (ts + 1 < TT) {
            #pragma unroll
            for (int r = 0; r < 4; ++r) {
                dnx[r].x = pkbf(pre[4*r+0], pre[4*r+1]);
                dnx[r].y = pkbf(pre[4*r+2], pre[4*r+3]);
            }
        }
        __syncthreads();   // A: all frag reads of xt complete
        if (ts + 1 < TT) {
            #pragma unroll
            for (int r = 0; r < 4; ++r) {
                int g = (4 * sw + r) ^ (sf & 15);
                *(int2*)&xt[sf * 64 + g * 4] = dnx[r];
            }
        }
        __syncthreads();   // B: next tile staged
    }
}

extern "C" void kernel_launch(void* const* d_in, const int* in_sizes, int n_in,
                              void* d_out, int out_size, void* d_ws, size_t ws_size,
                              hipStream_t stream) {
    (void)in_sizes; (void)n_in; (void)out_size; (void)d_ws; (void)ws_size;
    const float* x  = (const float*)d_in[0];
    const float* W  = (const float*)d_in[1];
    const float* Th = (const float*)d_in[2];
    float* o = (float*)d_out;
    gcjk_main<<<dim3(Bn * (Tn / TT)), dim3(256), 0, stream>>>(x, W, Th, o);
}

// Round 4
// 119.689 us; speedup vs baseline: 1.4842x; 1.4842x over previous
//
#include <hip/hip_runtime.h>
#include <stdint.h>
#include <stddef.h>

// Problem constants (match reference).
#define Bn 32
#define Tn 512
#define Vn 64
#define Fn 64
#define TT 32   // timesteps per workgroup -> grid = 32 * 16 = 512 blocks

typedef __attribute__((ext_vector_type(8))) short bfx8;  // 8 bf16 (4 VGPRs)
typedef __attribute__((ext_vector_type(4))) float fx4;   // fp32 x4 (indexable)
typedef __attribute__((ext_vector_type(4))) int   ix4;
typedef __attribute__((ext_vector_type(2))) int   ix2;

// fp32 -> bf16, round-to-nearest-even (scalar, setup paths only)
__device__ __forceinline__ short f2bf(float f) {
    union { float f; uint32_t u; } c; c.f = f;
    uint32_t u = c.u;
    return (short)((u + 0x7FFFu + ((u >> 16) & 1u)) >> 16);
}
// pack 2 fp32 -> dword {lo = bf16(a), hi = bf16(b)}, round-half-up.
// 2 int adds + 1 v_perm_b32; selector picks bytes {2,3} of a (S1, low dword)
// then bytes {2,3} of b (S0, high dword). No inline asm.
__device__ __forceinline__ int pkbf2(float a, float b) {
    uint32_t ua = __float_as_uint(a) + 0x8000u;
    uint32_t ub = __float_as_uint(b) + 0x8000u;
    return (int)__builtin_amdgcn_perm(ub, ua, 0x07060302u);
}

// Setup-phase data (wt/ps/dg) dies before Theta frags (tf) are written.
union Shmem {
    struct { float wt[64][65]; float ps[4][64]; float dg[64]; } s;  // 17920 B
    short tf[32][64][8];                                            // 32768 B
};

__global__ __launch_bounds__(256, 2) void gcjk_main(
    const float* __restrict__ x, const float* __restrict__ W,
    const float* __restrict__ Theta, float* __restrict__ out)
{
    __shared__ __align__(16) Shmem sm;
    __shared__ __align__(16) short xt[2][64 * 64];  // Xt[f][u] bf16, XOR-swizzled, dbuf

    const int tid  = threadIdx.x;
    const int lane = tid & 63;
    const int wv   = tid >> 6;
    const int l15  = lane & 15;
    const int gg   = lane >> 4;
    // staging mapping: thread owns a 4x4 patch (u0 = 4*sa, f0 = 4*sc)
    const int sc = tid & 15, sa = tid >> 4;

    const int bid = blockIdx.x;
    const int b   = bid >> 4;
    const int t0  = (bid & 15) * TT;

    // ---- setup: load W[b] into LDS ----
    const float4* W4 = (const float4*)(W + b * (Vn * Vn));
    #pragma unroll
    for (int c = 0; c < 4; ++c) {
        float4 wq = W4[c * 256 + tid];
        int flat = (c * 256 + tid) * 4;
        int i = flat >> 6, j = flat & 63;
        sm.s.wt[i][j+0] = wq.x; sm.s.wt[i][j+1] = wq.y;
        sm.s.wt[i][j+2] = wq.z; sm.s.wt[i][j+3] = wq.w;
    }
    __syncthreads();

    // column sums deg[j] = sum_i W[i][j]
    {
        float s = 0.f;
        #pragma unroll
        for (int r = 0; r < 16; ++r) s += sm.s.wt[wv * 16 + r][lane];
        sm.s.ps[wv][lane] = s;
    }
    __syncthreads();
    if (tid < 64) sm.s.dg[tid] = sm.s.ps[0][tid] + sm.s.ps[1][tid] + sm.s.ps[2][tid] + sm.s.ps[3][tid];
    __syncthreads();

    // ---- A fragments (stage-1 B-operand) in registers — R2-proven scalar path ----
    // af[k][s] element e = T_k[u = 32s+8gg+e][v = 16wv+l15]
    bfx8 af[4][2];
    {
        const int v = 16 * wv + l15;
        #pragma unroll
        for (int s = 0; s < 2; ++s) {
            #pragma unroll
            for (int e = 0; e < 8; ++e) {
                int u = 32 * s + 8 * gg + e;
                float wuv = sm.s.wt[u][v];
                float lt  = ((u == v) ? (sm.s.dg[u] - 1.0f) : 0.0f) - wuv;  // D - W - I
                float p0  = (u == v) ? 1.0f : 0.0f;
                float p1  = lt;
                float p2  = 2.0f * lt * p1 - p0;   // elementwise Chebyshev
                float p3  = 2.0f * lt * p2 - p1;
                af[0][s][e] = f2bf(p0);
                af[1][s][e] = f2bf(p1);
                af[2][s][e] = f2bf(p2);
                af[3][s][e] = f2bf(p3);
            }
        }
    }
    __syncthreads();   // wt/ps/dg dead; union becomes tf

    // ---- Theta fragments (stage-2 A-operand) into LDS — R2-proven scalar path ----
    #pragma unroll
    for (int fi = 0; fi < 8; ++fi) {
        int frag = wv * 8 + fi;
        int gt = frag >> 3, k = (frag >> 1) & 3, fh = frag & 1;
        int g  = 16 * gt + l15;
        #pragma unroll
        for (int e = 0; e < 8; ++e) {
            int f = 16 * (2 * fh + (e >> 2)) + 4 * gg + (e & 3);
            sm.tf[frag][lane][e] = f2bf(Theta[(k * Fn + f) * Fn + g]);
        }
    }

    // ---- initial staging of tile t0 into xt[0] ----
    const float* xs = x + (size_t)(b * Tn + t0) * (Vn * Fn);
    {
        fx4 xq[4];
        #pragma unroll
        for (int j = 0; j < 4; ++j) xq[j] = *(const fx4*)(xs + (4 * sa + j) * Fn + 4 * sc);
        #pragma unroll
        for (int r = 0; r < 4; ++r) {
            int f = 4 * sc + r;
            ix2 d; d[0] = pkbf2(xq[0][r], xq[1][r]); d[1] = pkbf2(xq[2][r], xq[3][r]);
            int g = sa ^ (f & 15);          // 8B-granule XOR swizzle
            *(ix2*)&xt[0][f * 64 + g * 4] = d;
        }
    }
    __syncthreads();

    // ---- main t loop: dbuf xt, 1 barrier/iter, early-issued global loads ----
    for (int ts = 0; ts < TT; ++ts) {
        const int cur = ts & 1;
        const float* xb = xs + (size_t)ts * (Vn * Fn);
        const int v = 16 * wv + l15;

        // early-issue: epilogue x re-read (L2/L3-hot) for the CURRENT tile
        fx4 ex[4];
        #pragma unroll
        for (int gt = 0; gt < 4; ++gt)
            ex[gt] = *(const fx4*)(xb + v * Fn + 16 * gt + 4 * gg);

        // early-issue: next tile's staging loads
        fx4 xq[4];
        if (ts + 1 < TT) {
            const float* xn = xb + (Vn * Fn);
            #pragma unroll
            for (int j = 0; j < 4; ++j) xq[j] = *(const fx4*)(xn + (4 * sa + j) * Fn + 4 * sc);
        }

        // X fragments from LDS (swizzled b64 pairs)
        const short* xcur = xt[cur];
        bfx8 xf[4][2];
        #pragma unroll
        for (int ft = 0; ft < 4; ++ft) {
            #pragma unroll
            for (int s = 0; s < 2; ++s) {
                int ub = 8 * s + 2 * gg;
                int g0 = ub ^ l15, g1 = (ub + 1) ^ l15;
                ix2 lo = *(const ix2*)&xcur[(16 * ft + l15) * 64 + g0 * 4];
                ix2 hi = *(const ix2*)&xcur[(16 * ft + l15) * 64 + g1 * 4];
                ix4 q; q[0] = lo[0]; q[1] = lo[1]; q[2] = hi[0]; q[3] = hi[1];
                xf[ft][s] = *(bfx8*)&q;
            }
        }

        fx4 oacc[4] = {fx4{0,0,0,0}, fx4{0,0,0,0}, fx4{0,0,0,0}, fx4{0,0,0,0}};
        #pragma unroll
        for (int k = 0; k < 4; ++k) {
            // stage 1: PT_k[f][v] = sum_u Xt[f][u] * T_k[u][v]
            fx4 pacc[4] = {fx4{0,0,0,0}, fx4{0,0,0,0}, fx4{0,0,0,0}, fx4{0,0,0,0}};
            #pragma unroll
            for (int ft = 0; ft < 4; ++ft) {
                pacc[ft] = __builtin_amdgcn_mfma_f32_16x16x32_bf16(xf[ft][0], af[k][0], pacc[ft], 0, 0, 0);
                pacc[ft] = __builtin_amdgcn_mfma_f32_16x16x32_bf16(xf[ft][1], af[k][1], pacc[ft], 0, 0, 0);
            }
            // stage 2: out'[g][v] += Theta'[g][kf] * PT[kf][v] (register repack via perm)
            #pragma unroll
            for (int fh = 0; fh < 2; ++fh) {
                fx4 pa = pacc[2*fh], pb = pacc[2*fh+1];
                ix4 pq;
                pq[0] = pkbf2(pa[0], pa[1]); pq[1] = pkbf2(pa[2], pa[3]);
                pq[2] = pkbf2(pb[0], pb[1]); pq[3] = pkbf2(pb[2], pb[3]);
                bfx8 pf = *(bfx8*)&pq;
                #pragma unroll
                for (int gt = 0; gt < 4; ++gt) {
                    bfx8 th = *(const bfx8*)&sm.tf[gt*8 + k*2 + fh][lane][0];
                    oacc[gt] = __builtin_amdgcn_mfma_f32_16x16x32_bf16(th, pf, oacc[gt], 0, 0, 0);
                }
            }
        }

        // epilogue: relu(out) + sigmoid(x) with the pre-loaded ex
        {
            float* ob = out + (size_t)(b * Tn + t0 + ts) * (Vn * Fn);
            #pragma unroll
            for (int gt = 0; gt < 4; ++gt) {
                fx4 xv = ex[gt];
                fx4 o  = oacc[gt];
                fx4 r;
                #pragma unroll
                for (int j = 0; j < 4; ++j)
                    r[j] = fmaxf(o[j], 0.f) + __builtin_amdgcn_rcpf(1.f + __expf(-xv[j]));
                *(fx4*)(ob + v * Fn + 16 * gt + 4 * gg) = r;
            }
        }

        // write-late: pack + commit next tile into the other buffer
        if (ts + 1 < TT) {
            short* xnext = xt[cur ^ 1];
            #pragma unroll
            for (int r = 0; r < 4; ++r) {
                int f = 4 * sc + r;
                ix2 d; d[0] = pkbf2(xq[0][r], xq[1][r]); d[1] = pkbf2(xq[2][r], xq[3][r]);
                int g = sa ^ (f & 15);
                *(ix2*)&xt[cur ^ 1][f * 64 + g * 4] = d;
            }
            (void)xnext;
        }
        __syncthreads();
    }
}

extern "C" void kernel_launch(void* const* d_in, const int* in_sizes, int n_in,
                              void* d_out, int out_size, void* d_ws, size_t ws_size,
                              hipStream_t stream) {
    (void)in_sizes; (void)n_in; (void)out_size; (void)d_ws; (void)ws_size;
    const float* x  = (const float*)d_in[0];
    const float* W  = (const float*)d_in[1];
    const float* Th = (const float*)d_in[2];
    float* o = (float*)d_out;
    gcjk_main<<<dim3(Bn * (Tn / TT)), dim3(256), 0, stream>>>(x, W, Th, o);
}